// Round 12
// baseline (236.412 us; speedup 1.0000x reference)
//
#include <hip/hip_runtime.h>

#define B_    4
#define DEC_  256
#define ENC_  1024
#define D_    1024
#define A_    144
#define V_    50257
#define NROW_ (B_ * DEC_)
#define CH_   32         // vocab chunks per row
#define CW_   1572       // chunk width: 32*1572 = 50304 >= V_

typedef __attribute__((ext_vector_type(4))) float float4v;

// ---------------- single fused kernel ----------------
// block = (row, chunk). Phases:
//  A: init LDS (vec zero sAdd); p_gen dot (redundant per block, deterministic);
//     scan row's 1024 ids -> sList via per-wave ballot compaction
//  B: issue global_load_lds staging of ovp chunk -> sOvp (hides under the dots);
//     att-dot for listed e's (4 lanes/e, nontemporal) -> ds_add_f32 into sAdd
//  C: out[chunk] = pg*sOvp + sAdd   (LDS reads + nontemporal coalesced writes)
__global__ __launch_bounds__(256) void k_merge(const int* __restrict__ ids,
                                               const float* __restrict__ att,
                                               const float* __restrict__ hid,
                                               const float* __restrict__ ovp,
                                               const float* __restrict__ Wp,
                                               const float* __restrict__ bp,
                                               const float* __restrict__ Wa,
                                               const float* __restrict__ ba,
                                               float* __restrict__ out,
                                               float* __restrict__ tail){
  __shared__ float sW[A_];
  __shared__ float red[4];
  __shared__ __align__(16) float sAdd[CW_ + 8];
  __shared__ __align__(16) float sOvp[CW_ + 4];
  __shared__ unsigned sList[ENC_];
  __shared__ int sCnt;

  int t = threadIdx.x;
  unsigned blk   = blockIdx.x;
  unsigned row   = blk >> 5;                  // / CH_
  unsigned chunk = blk & (CH_ - 1);
  unsigned bb    = row >> 8;                  // / DEC_
  unsigned q0    = chunk * CW_;
  unsigned qlen  = (chunk == CH_ - 1) ? (V_ - q0) : CW_;   // 1525 on last chunk

  size_t gs   = (size_t)row * V_ + q0;
  size_t ge   = gs + qlen;
  size_t gs4  = gs & ~(size_t)3;
  size_t beg4 = (gs + 3) & ~(size_t)3;
  size_t end4 = ge & ~(size_t)3;
  unsigned phase = (unsigned)(gs - gs4);      // 0..3
  unsigned lbase = (unsigned)(beg4 - gs4);    // 0 or 4
  unsigned n4    = (unsigned)((end4 - beg4) >> 2);
  int nhead = (int)(beg4 - gs);
  int ntail = (int)(ge - end4);

  // ---- phase A: init + p_gen dot + ballot list build ----
  if (t < A_) sW[t] = Wa[t];
  if (t == 0) sCnt = 0;
  {
    float4v z; z[0] = 0.f; z[1] = 0.f; z[2] = 0.f; z[3] = 0.f;
    float4v* za = reinterpret_cast<float4v*>(sAdd);
    for (int i = t; i < (CW_ + 8) / 4; i += 256) za[i] = z;
  }
  {
    float4v hv = reinterpret_cast<const float4v*>(hid + (size_t)row * D_)[t];
    float4v wv = reinterpret_cast<const float4v*>(Wp)[t];
    float s = hv[0]*wv[0] + hv[1]*wv[1] + hv[2]*wv[2] + hv[3]*wv[3];
    for (int o = 32; o > 0; o >>= 1) s += __shfl_down(s, o, 64);
    if ((t & 63) == 0) red[t >> 6] = s;
  }
  __syncthreads();
  float pg = 1.f / (1.f + __expf(-(red[0] + red[1] + red[2] + red[3] + bp[0])));
  if (chunk == 0 && t == 0) tail[row] = pg;

  unsigned lane = (unsigned)t & 63u;
#pragma unroll
  for (int k = 0; k < 4; ++k){
    int e = k * 256 + t;
    unsigned id = (unsigned)ids[bb * ENC_ + e];
    unsigned rel = id - q0;                   // unsigned wrap handles id < q0
    bool hit = rel < qlen;
    unsigned long long m = __ballot(hit);
    int base = 0;
    if (lane == 0 && m) base = atomicAdd(&sCnt, __popcll(m));
    base = __shfl(base, 0, 64);
    if (hit){
      int off = __popcll(m & ((1ull << lane) - 1ull));
      sList[base + off] = (rel << 10) | (unsigned)e;   // rel<1572 (11b) | e (10b)
    }
  }
  __syncthreads();

  // ---- phase B: async ovp staging, then att dots ----
  const float4v* src = reinterpret_cast<const float4v*>(ovp + beg4);
  {
    unsigned wave = (unsigned)t >> 6;
    unsigned ncall = (n4 + 63u) >> 6;         // <= 7
    for (unsigned c = wave; c < ncall; c += 4){
      unsigned idx = c * 64u + lane;
      if (idx < n4)
        __builtin_amdgcn_global_load_lds(
            (const unsigned int*)(src + idx),
            (unsigned int*)((char*)sOvp + (size_t)c * 1024),
            16, 0, 0);
    }
  }
  float preH = (t < nhead) ? ovp[gs + t]   : 0.f;
  float preT = (t < ntail) ? ovp[end4 + t] : 0.f;

  int cnt = sCnt;
  unsigned lane4 = (unsigned)t & 3u;
  float bav = ba[0];
  float one_m = 1.f - pg;
  size_t rowENC = (size_t)row * ENC_;
  for (int g = t >> 2; g < cnt; g += 64){
    unsigned pk  = sList[g];
    unsigned e   = pk & 1023u;
    unsigned rel = pk >> 10;
    const float4v* ap = reinterpret_cast<const float4v*>(att + (rowENC + e) * A_);
    float acc0 = 0.f, acc1 = 0.f;
#pragma unroll
    for (int j = 0; j < 9; ++j){
      float4v v = __builtin_nontemporal_load(&ap[lane4 + 4u*j]);
      const float* w = &sW[4u*(lane4 + 4u*j)];
      float p = v[0]*w[0] + v[1]*w[1] + v[2]*w[2] + v[3]*w[3];
      if (j & 1) acc1 += p; else acc0 += p;
    }
    float acc = acc0 + acc1;
    acc += __shfl_xor(acc, 1, 64);
    acc += __shfl_xor(acc, 2, 64);
    if (lane4 == 0){
      float x = acc + bav;
      x = x > 0.f ? x : 0.f;
      atomicAdd(&sAdd[rel + phase], one_m * x);   // ds_add_f32
    }
  }
  __syncthreads();   // sAdd complete; vmcnt(0) drain completes sOvp staging

  // ---- phase C: stream chunk (LDS -> global, nontemporal writes) ----
  if (t < nhead) __builtin_nontemporal_store(pg * preH + sAdd[phase + (unsigned)t], &out[gs + t]);
  if (t < ntail) __builtin_nontemporal_store(pg * preT + sAdd[lbase + 4u*n4 + (unsigned)t], &out[end4 + t]);
  float4v* dst = reinterpret_cast<float4v*>(out + beg4);
  const float4v* sOvpV = reinterpret_cast<const float4v*>(sOvp);
  for (unsigned i = t; i < n4; i += 256){
    float4v a  = sOvpV[i];
    float4v sa = *reinterpret_cast<const float4v*>(&sAdd[lbase + 4u*i]);
    float4v o;
    o[0] = pg*a[0] + sa[0];
    o[1] = pg*a[1] + sa[1];
    o[2] = pg*a[2] + sa[2];
    o[3] = pg*a[3] + sa[3];
    __builtin_nontemporal_store(o, &dst[i]);
  }
}

extern "C" void kernel_launch(void* const* d_in, const int* in_sizes, int n_in,
                              void* d_out, int out_size, void* d_ws, size_t ws_size,
                              hipStream_t stream) {
  (void)in_sizes; (void)n_in; (void)d_ws; (void)ws_size; (void)out_size;
  const int*   ids = (const int*)  d_in[0];
  const float* att = (const float*)d_in[1];
  const float* hid = (const float*)d_in[2];
  const float* ovp = (const float*)d_in[3];
  const float* Wp  = (const float*)d_in[4];
  const float* bp  = (const float*)d_in[5];
  const float* Wa  = (const float*)d_in[6];
  const float* ba  = (const float*)d_in[7];
  float* out  = (float*)d_out;
  float* tail = out + (size_t)NROW_ * V_;   // p_gen output (fp32)

  k_merge<<<NROW_ * CH_, 256, 0, stream>>>(ids, att, hid, ovp, Wp, bp, Wa, ba, out, tail);
}

// Round 13
// 188.853 us; speedup vs baseline: 1.2518x; 1.2518x over previous
//
#include <hip/hip_runtime.h>

#define B_    4
#define DEC_  256
#define ENC_  1024
#define D_    1024
#define A_    144
#define V_    50257
#define NROW_ (B_ * DEC_)
#define CH_   16         // vocab chunks per row
#define CW_   3144       // chunk width: 16*3144 = 50304 >= V_, multiple of 8

typedef __attribute__((ext_vector_type(4))) float float4v;

// ---------------- single fused kernel (r11 configuration, proven 188.5 us) ----------------
// block = (row, chunk). Phases:
//  A: init LDS (vec zero sAdd); p_gen dot (redundant per block, deterministic);
//     scan row's 1024 ids -> sList of in-chunk entries
//  B: issue global_load_lds staging of ovp chunk -> sOvp (hides under the dots);
//     att-dot for listed e's (4 lanes/e) -> ds_add_f32 into sAdd
//  C: out[chunk] = pg*sOvp + sAdd   (LDS reads + nontemporal coalesced writes)
__global__ __launch_bounds__(256) void k_merge(const int* __restrict__ ids,
                                               const float* __restrict__ att,
                                               const float* __restrict__ hid,
                                               const float* __restrict__ ovp,
                                               const float* __restrict__ Wp,
                                               const float* __restrict__ bp,
                                               const float* __restrict__ Wa,
                                               const float* __restrict__ ba,
                                               float* __restrict__ out,
                                               float* __restrict__ tail){
  __shared__ float sW[A_];
  __shared__ float red[4];
  __shared__ __align__(16) float sAdd[CW_ + 8];
  __shared__ __align__(16) float sOvp[CW_ + 4];
  __shared__ unsigned sList[ENC_];
  __shared__ int sCnt;

  int t = threadIdx.x;
  unsigned blk   = blockIdx.x;
  unsigned row   = blk >> 4;                  // / CH_
  unsigned chunk = blk & (CH_ - 1);
  unsigned bb    = row >> 8;                  // / DEC_
  unsigned q0    = chunk * CW_;
  unsigned qlen  = (chunk == CH_ - 1) ? (V_ - q0) : CW_;   // 3097 on last chunk

  size_t gs   = (size_t)row * V_ + q0;
  size_t ge   = gs + qlen;
  size_t gs4  = gs & ~(size_t)3;
  size_t beg4 = (gs + 3) & ~(size_t)3;
  size_t end4 = ge & ~(size_t)3;
  unsigned phase = (unsigned)(gs - gs4);      // 0..3
  unsigned lbase = (unsigned)(beg4 - gs4);    // 0 or 4
  unsigned n4    = (unsigned)((end4 - beg4) >> 2);
  int nhead = (int)(beg4 - gs);
  int ntail = (int)(ge - end4);

  // ---- phase A: init + p_gen dot ----
  if (t < A_) sW[t] = Wa[t];
  if (t == 0) sCnt = 0;
  {
    float4v z; z[0] = 0.f; z[1] = 0.f; z[2] = 0.f; z[3] = 0.f;
    float4v* za = reinterpret_cast<float4v*>(sAdd);
    for (int i = t; i < (CW_ + 8) / 4; i += 256) za[i] = z;
  }
  {
    float4v hv = reinterpret_cast<const float4v*>(hid + (size_t)row * D_)[t];
    float4v wv = reinterpret_cast<const float4v*>(Wp)[t];
    float s = hv[0]*wv[0] + hv[1]*wv[1] + hv[2]*wv[2] + hv[3]*wv[3];
    for (int o = 32; o > 0; o >>= 1) s += __shfl_down(s, o, 64);
    if ((t & 63) == 0) red[t >> 6] = s;
  }
  __syncthreads();
  float pg = 1.f / (1.f + __expf(-(red[0] + red[1] + red[2] + red[3] + bp[0])));
  if (chunk == 0 && t == 0) tail[row] = pg;

#pragma unroll
  for (int k = 0; k < 4; ++k){
    int e = k * 256 + t;
    unsigned id = (unsigned)ids[bb * ENC_ + e];
    unsigned rel = id - q0;                   // unsigned wrap handles id < q0
    if (rel < qlen){
      int p = atomicAdd(&sCnt, 1);
      sList[p] = (rel << 10) | (unsigned)e;   // rel<3144 (12b) | e (10b)
    }
  }
  __syncthreads();

  // ---- phase B: async ovp staging, then att dots ----
  const float4v* src = reinterpret_cast<const float4v*>(ovp + beg4);
  {
    unsigned wave = (unsigned)t >> 6, lane = (unsigned)t & 63u;
    unsigned ncall = (n4 + 63u) >> 6;         // <= 13
    for (unsigned c = wave; c < ncall; c += 4){
      unsigned idx = c * 64u + lane;
      if (idx < n4)
        __builtin_amdgcn_global_load_lds(
            (const unsigned int*)(src + idx),
            (unsigned int*)((char*)sOvp + (size_t)c * 1024),
            16, 0, 0);
    }
  }
  float preH = (t < nhead) ? ovp[gs + t]   : 0.f;
  float preT = (t < ntail) ? ovp[end4 + t] : 0.f;

  int cnt = sCnt;
  unsigned lane4 = (unsigned)t & 3u;
  float bav = ba[0];
  float one_m = 1.f - pg;
  size_t rowENC = (size_t)row * ENC_;
  for (int g = t >> 2; g < cnt; g += 64){
    unsigned pk  = sList[g];
    unsigned e   = pk & 1023u;
    unsigned rel = pk >> 10;
    const float4v* ap = reinterpret_cast<const float4v*>(att + (rowENC + e) * A_);
    float acc0 = 0.f, acc1 = 0.f;
#pragma unroll
    for (int j = 0; j < 9; ++j){
      float4v v = ap[lane4 + 4u*j];
      const float* w = &sW[4u*(lane4 + 4u*j)];
      float p = v[0]*w[0] + v[1]*w[1] + v[2]*w[2] + v[3]*w[3];
      if (j & 1) acc1 += p; else acc0 += p;
    }
    float acc = acc0 + acc1;
    acc += __shfl_xor(acc, 1, 64);
    acc += __shfl_xor(acc, 2, 64);
    if (lane4 == 0){
      float x = acc + bav;
      x = x > 0.f ? x : 0.f;
      atomicAdd(&sAdd[rel + phase], one_m * x);   // ds_add_f32
    }
  }
  __syncthreads();   // sAdd complete; vmcnt(0) drain completes sOvp staging

  // ---- phase C: stream chunk (LDS -> global, nontemporal writes) ----
  if (t < nhead) __builtin_nontemporal_store(pg * preH + sAdd[phase + (unsigned)t], &out[gs + t]);
  if (t < ntail) __builtin_nontemporal_store(pg * preT + sAdd[lbase + 4u*n4 + (unsigned)t], &out[end4 + t]);
  float4v* dst = reinterpret_cast<float4v*>(out + beg4);
  const float4v* sOvpV = reinterpret_cast<const float4v*>(sOvp);
  for (unsigned i = t; i < n4; i += 256){
    float4v a  = sOvpV[i];
    float4v sa = *reinterpret_cast<const float4v*>(&sAdd[lbase + 4u*i]);
    float4v o;
    o[0] = pg*a[0] + sa[0];
    o[1] = pg*a[1] + sa[1];
    o[2] = pg*a[2] + sa[2];
    o[3] = pg*a[3] + sa[3];
    __builtin_nontemporal_store(o, &dst[i]);
  }
}

extern "C" void kernel_launch(void* const* d_in, const int* in_sizes, int n_in,
                              void* d_out, int out_size, void* d_ws, size_t ws_size,
                              hipStream_t stream) {
  (void)in_sizes; (void)n_in; (void)d_ws; (void)ws_size; (void)out_size;
  const int*   ids = (const int*)  d_in[0];
  const float* att = (const float*)d_in[1];
  const float* hid = (const float*)d_in[2];
  const float* ovp = (const float*)d_in[3];
  const float* Wp  = (const float*)d_in[4];
  const float* bp  = (const float*)d_in[5];
  const float* Wa  = (const float*)d_in[6];
  const float* ba  = (const float*)d_in[7];
  float* out  = (float*)d_out;
  float* tail = out + (size_t)NROW_ * V_;   // p_gen output (fp32)

  k_merge<<<NROW_ * CH_, 256, 0, stream>>>(ids, att, hid, ovp, Wp, bp, Wa, ba, out, tail);
}